// Round 3
// baseline (191.680 us; speedup 1.0000x reference)
//
#include <hip/hip_runtime.h>

// InnerProduct: lp[r,p] = sum_f w[p,f]^2 * sum_e x[r,f,e]^2
// R=32768, F=64, E=16, P=10. HBM floor: 134 MB read + 1.3 MB write ~= 20 us.
//
// v3: discriminator between "already at floor" and "latency-limited".
//  - R1's perfect coalescing: lane i reads xrow[seg*64+i] (float4), 1 KiB/instr
//  - R2's load ILP: 16 independent float4 loads in flight per thread
//  - shuffle chain cut 6 hops -> 2 (masks 1,2; 16 independent chains)
//  - f-reduction via LDS phase-B (pitch 68 floats = 272 B: b128-aligned,
//    conflict-free for lanes differing in r: 68%32=4, r*4 distinct mod 32)
constexpr int F = 64;
constexpr int E = 16;
constexpr int P = 10;
constexpr int TILE_ROWS = 16;
constexpr int PITCH = 68;

__global__ __launch_bounds__(256, 4) void ip_kernel(const float* __restrict__ x,
                                                    const float* __restrict__ w,
                                                    float* __restrict__ out) {
    __shared__ float xsq_s[TILE_ROWS][PITCH];
    __shared__ float wsq_s[P][PITCH];

    const int tid = threadIdx.x;
    const int lane = tid & 63;
    const int wv = tid >> 6;   // wave 0..3: rows wv*4 .. wv*4+3 of the tile
    const int q = lane & 3;    // e-quad
    const int g = lane >> 2;   // f mod 16

    // Squared weights -> LDS (overlaps phase-A loads; covered by the barrier).
    for (int idx = tid; idx < P * F; idx += 256) {
        const float t = w[idx];
        wsq_s[idx >> 6][idx & 63] = t * t;
    }

    const int tile = blockIdx.x;  // grid == n_tiles, one tile per block
    const float* xt = x + (size_t)tile * (TILE_ROWS * F * E);

    // ---- Phase A: 16 independent, perfectly-coalesced float4 loads ----
    float4 v[4][4];
#pragma unroll
    for (int k = 0; k < 4; ++k) {
        const float4* xrow = (const float4*)(xt + (size_t)(wv * 4 + k) * (F * E));
#pragma unroll
        for (int seg = 0; seg < 4; ++seg)
            v[k][seg] = xrow[seg * 64 + lane];  // lane-contiguous: 1 KiB/instr
    }
    // Square-reduce: per-lane dot4, then 2-hop xor combine (16 indep chains).
    float sq[4][4];
#pragma unroll
    for (int k = 0; k < 4; ++k) {
#pragma unroll
        for (int seg = 0; seg < 4; ++seg) {
            const float4 t = v[k][seg];
            float s = t.x * t.x + t.y * t.y + t.z * t.z + t.w * t.w;
            s += __shfl_xor(s, 1);
            s += __shfl_xor(s, 2);
            sq[k][seg] = s;  // = xsq[row wv*4+k][f = seg*16+g], all lanes
        }
    }
    if (q == 0) {
#pragma unroll
        for (int k = 0; k < 4; ++k)
#pragma unroll
            for (int seg = 0; seg < 4; ++seg)
                xsq_s[wv * 4 + k][seg * 16 + g] = sq[k][seg];
    }
    __syncthreads();

    // ---- Phase B: lp[r][p] = sum_f wsq[p][f] * xsq[r][f] ----
    if (tid < TILE_ROWS * P) {
        const int r = tid / P;
        const int p = tid % P;
        float acc = 0.0f;
#pragma unroll
        for (int f4 = 0; f4 < F; f4 += 4) {
            const float4 xa = *(const float4*)&xsq_s[r][f4];
            const float4 wa = *(const float4*)&wsq_s[p][f4];
            acc += xa.x * wa.x + xa.y * wa.y + xa.z * wa.z + xa.w * wa.w;
        }
        out[(size_t)tile * (TILE_ROWS * P) + tid] = acc;  // 640 B contiguous
    }
}

extern "C" void kernel_launch(void* const* d_in, const int* in_sizes, int n_in,
                              void* d_out, int out_size, void* d_ws, size_t ws_size,
                              hipStream_t stream) {
    const float* x = (const float*)d_in[0];
    const float* w = (const float*)d_in[1];
    float* out = (float*)d_out;
    const int rows = in_sizes[0] / (F * E);   // 32768
    const int n_tiles = rows / TILE_ROWS;     // 2048

    dim3 grid(n_tiles), block(256);
    hipLaunchKernelGGL(ip_kernel, grid, block, 0, stream, x, w, out);
}